// Round 5
// baseline (995.045 us; speedup 1.0000x reference)
//
#include <hip/hip_runtime.h>
#include <math.h>
#include <stdint.h>

// Problem dims (fixed by reference)
static constexpr int Bb  = 4;
static constexpr int Ll  = 4096;
static constexpr int Dd  = 1024;
static constexpr int DFF = 4096;
static constexpr int Mm  = Bb * Ll;     // 16384 rows
static constexpr int CH  = 64;          // scan chunks
static constexpr int CS  = Ll / CH;     // 64 steps per chunk
static constexpr float EPS = 1e-6f;

typedef __attribute__((ext_vector_type(8))) short short8;     // 8 bf16 (4 VGPRs)
typedef __attribute__((ext_vector_type(4))) float floatx4;    // MFMA C/D
typedef __attribute__((ext_vector_type(4))) unsigned short us4;

__device__ __forceinline__ float sigmoidf_(float v) { return 1.0f / (1.0f + __expf(-v)); }
// safe at +-inf: 2*sigmoid(2x)-1
__device__ __forceinline__ float fast_tanh(float x) {
    return 2.0f / (1.0f + __expf(-2.0f * x)) - 1.0f;
}
__device__ __forceinline__ ushort f2bf(float f) {
    union { float f; uint32_t u; } v; v.f = f;
    return (ushort)((v.u + 0x7FFFu + ((v.u >> 16) & 1u)) >> 16);   // RNE
}
__device__ __forceinline__ float bf2f(ushort h) {
    union { uint32_t u; float f; } v; v.u = (uint32_t)h << 16; return v.f;
}

// async global->LDS, 16 bytes per lane (wave-uniform base + lane*16 layout)
__device__ __forceinline__ void gload16(const ushort* g, ushort* l) {
    __builtin_amdgcn_global_load_lds(
        (const __attribute__((address_space(1))) uint32_t*)g,
        (__attribute__((address_space(3))) uint32_t*)l, 16, 0, 0);
}

// ---------------------------------------------------------------------------
// Stage bf16 tiles into LDS, layout [m][32k] with 16B-chunk XOR swizzle:
// lds chunk (m*4 + slot) holds global k-block (slot ^ ((m>>1)&3)).
// 2-way LDS bank aliasing on fragment ds_read_b128 = free (m136).
// ---------------------------------------------------------------------------
__device__ __forceinline__ void stage128x32(const ushort* __restrict__ src, int ld,
                                            int r0, int k0, ushort* lds, int tid)
{
    #pragma unroll
    for (int h = 0; h < 2; ++h) {
        int c  = tid + h * 256;            // chunk 0..511
        int m  = c >> 2;
        int kb = (c & 3) ^ ((m >> 1) & 3);
        gload16(src + (size_t)(r0 + m) * ld + k0 + kb * 8, lds + c * 8);
    }
}

__device__ __forceinline__ void stage64x32(const ushort* __restrict__ src, int ld,
                                           int r0, int k0, ushort* lds, int tid)
{
    int c  = tid;                          // chunk 0..255
    int m  = c >> 2;                       // 0..63
    int kb = (c & 3) ^ ((m >> 1) & 3);
    gload16(src + (size_t)(r0 + m) * ld + k0 + kb * 8, lds + c * 8);
}

// ---------------------------------------------------------------------------
// Fused QuasiLSTM gate GEMM (dual, shared A).  N space = 2048:
//   W1t rows [0,1024) = w_input^T,  [1024,2048) = w_forget^T
//   W2t rows [0,1024) = w_igate^T,  [1024,2048) = w_ogate^T
// col <  1024:  Gb  = tanh(z1) * sigmoid(z2)
// col >= 1024:  Ga  = sigmoid(z1);  Gog = sigmoid(z2)
// Block tile 128m x 64n, wave tile 64m x 32n, acc = 64 AGPR -> 3 waves/SIMD.
// ---------------------------------------------------------------------------
__global__ __launch_bounds__(256, 3) void mfma_gemm_gates(
    const ushort* __restrict__ A, const ushort* __restrict__ W1t,
    const ushort* __restrict__ W2t,
    const float* __restrict__ b_input, const float* __restrict__ b_forget,
    const float* __restrict__ b_igate, const float* __restrict__ b_ogate,
    ushort* __restrict__ Ga, ushort* __restrict__ Gb, ushort* __restrict__ Gog,
    int K)
{
    __shared__ ushort As[128 * 32];   // 8 KB
    __shared__ ushort B1s[64 * 32];   // 4 KB
    __shared__ ushort B2s[64 * 32];   // 4 KB
    int tid = threadIdx.x;
    int m0 = blockIdx.y * 128, n0 = blockIdx.x * 64;
    int wave = tid >> 6, lane = tid & 63;
    int wm = (wave >> 1) * 64, wn = (wave & 1) * 32;
    int fr = lane & 15, q = lane >> 4;
    int sw = (q ^ ((fr >> 1) & 3)) * 8;

    floatx4 acc1[4][2] = {};
    floatx4 acc2[4][2] = {};

    for (int k0 = 0; k0 < K; k0 += 32) {
        stage128x32(A,   K, m0, k0, As,  tid);
        stage64x32(W1t, K, n0, k0, B1s, tid);
        stage64x32(W2t, K, n0, k0, B2s, tid);
        __syncthreads();
        short8 a[4], b[2], c[2];
        #pragma unroll
        for (int mi = 0; mi < 4; ++mi)
            a[mi] = *(const short8*)&As[(wm + mi * 16 + fr) * 32 + sw];
        #pragma unroll
        for (int ni = 0; ni < 2; ++ni) {
            b[ni] = *(const short8*)&B1s[(wn + ni * 16 + fr) * 32 + sw];
            c[ni] = *(const short8*)&B2s[(wn + ni * 16 + fr) * 32 + sw];
        }
        #pragma unroll
        for (int mi = 0; mi < 4; ++mi)
            #pragma unroll
            for (int ni = 0; ni < 2; ++ni) {
                acc1[mi][ni] = __builtin_amdgcn_mfma_f32_16x16x32_bf16(
                    a[mi], b[ni], acc1[mi][ni], 0, 0, 0);
                acc2[mi][ni] = __builtin_amdgcn_mfma_f32_16x16x32_bf16(
                    a[mi], c[ni], acc2[mi][ni], 0, 0, 0);
            }
        __syncthreads();
    }

    if (n0 < 1024) {
        #pragma unroll
        for (int ni = 0; ni < 2; ++ni) {
            int col = n0 + wn + ni * 16 + fr;
            float b1v = b_input[col], b2v = b_igate[col];
            #pragma unroll
            for (int mi = 0; mi < 4; ++mi)
                #pragma unroll
                for (int r = 0; r < 4; ++r) {
                    int row = m0 + wm + mi * 16 + q * 4 + r;
                    float z1 = acc1[mi][ni][r] + b1v;
                    float z2 = acc2[mi][ni][r] + b2v;
                    Gb[(size_t)row * Dd + col] = f2bf(fast_tanh(z1) * sigmoidf_(z2));
                }
        }
    } else {
        #pragma unroll
        for (int ni = 0; ni < 2; ++ni) {
            int c2 = n0 - 1024 + wn + ni * 16 + fr;
            float b1v = b_forget[c2], b2v = b_ogate[c2];
            #pragma unroll
            for (int mi = 0; mi < 4; ++mi)
                #pragma unroll
                for (int r = 0; r < 4; ++r) {
                    int row = m0 + wm + mi * 16 + q * 4 + r;
                    float z1 = acc1[mi][ni][r] + b1v;
                    float z2 = acc2[mi][ni][r] + b2v;
                    Ga[(size_t)row * Dd + c2]  = f2bf(sigmoidf_(z1));
                    Gog[(size_t)row * Dd + c2] = f2bf(sigmoidf_(z2));
                }
        }
    }
}

// ---------------------------------------------------------------------------
// MFMA dual GEMM for SwiGLU: C = (A@W1+b1) * silu(A@W2+b2), bf16 out
// Block tile 128m x 64n, wave tile 64m x 32n (same occupancy layout as gates).
// ---------------------------------------------------------------------------
__global__ __launch_bounds__(256, 3) void mfma_gemm_swiglu(
    const ushort* __restrict__ A, const ushort* __restrict__ W1t,
    const float* __restrict__ b1, const ushort* __restrict__ W2t,
    const float* __restrict__ b2, ushort* __restrict__ C,
    int K, int ldC)
{
    __shared__ ushort As[128 * 32];
    __shared__ ushort B1s[64 * 32];
    __shared__ ushort B2s[64 * 32];
    int tid = threadIdx.x;
    int m0 = blockIdx.y * 128, n0 = blockIdx.x * 64;
    int wave = tid >> 6, lane = tid & 63;
    int wm = (wave >> 1) * 64, wn = (wave & 1) * 32;
    int fr = lane & 15, q = lane >> 4;
    int sw = (q ^ ((fr >> 1) & 3)) * 8;

    floatx4 acc1[4][2] = {};
    floatx4 acc2[4][2] = {};

    for (int k0 = 0; k0 < K; k0 += 32) {
        stage128x32(A,   K, m0, k0, As,  tid);
        stage64x32(W1t, K, n0, k0, B1s, tid);
        stage64x32(W2t, K, n0, k0, B2s, tid);
        __syncthreads();
        short8 a[4], b[2], c[2];
        #pragma unroll
        for (int mi = 0; mi < 4; ++mi)
            a[mi] = *(const short8*)&As[(wm + mi * 16 + fr) * 32 + sw];
        #pragma unroll
        for (int ni = 0; ni < 2; ++ni) {
            b[ni] = *(const short8*)&B1s[(wn + ni * 16 + fr) * 32 + sw];
            c[ni] = *(const short8*)&B2s[(wn + ni * 16 + fr) * 32 + sw];
        }
        #pragma unroll
        for (int mi = 0; mi < 4; ++mi)
            #pragma unroll
            for (int ni = 0; ni < 2; ++ni) {
                acc1[mi][ni] = __builtin_amdgcn_mfma_f32_16x16x32_bf16(
                    a[mi], b[ni], acc1[mi][ni], 0, 0, 0);
                acc2[mi][ni] = __builtin_amdgcn_mfma_f32_16x16x32_bf16(
                    a[mi], c[ni], acc2[mi][ni], 0, 0, 0);
            }
        __syncthreads();
    }

    #pragma unroll
    for (int ni = 0; ni < 2; ++ni) {
        int col = n0 + wn + ni * 16 + fr;
        float b1v = b1[col], b2v = b2[col];
        #pragma unroll
        for (int mi = 0; mi < 4; ++mi)
            #pragma unroll
            for (int r = 0; r < 4; ++r) {
                int row = m0 + wm + mi * 16 + q * 4 + r;
                float z1 = acc1[mi][ni][r] + b1v;
                float z2 = acc2[mi][ni][r] + b2v;
                C[(size_t)row * ldC + col] = f2bf(z1 * z2 * sigmoidf_(z2));
            }
    }
}

// ---------------------------------------------------------------------------
// MFMA residual GEMM: out_f32 = A_bf16[M,K] @ Wt[N,K]^T + bias + R (R == out)
// 128x128 block, 64x64 per wave (m97 structure — already at plateau).
// ---------------------------------------------------------------------------
__global__ __launch_bounds__(256, 2) void mfma_gemm_residual(
    const ushort* __restrict__ A, const ushort* __restrict__ Wt,
    const float* __restrict__ bias, float* __restrict__ C,
    int K, int ldC)
{
    __shared__ ushort As[128 * 32];
    __shared__ ushort Bs[128 * 32];
    int tid = threadIdx.x;
    int m0 = blockIdx.y * 128, n0 = blockIdx.x * 128;
    int wave = tid >> 6, lane = tid & 63;
    int wm = (wave >> 1) * 64, wn = (wave & 1) * 64;
    int fr = lane & 15, q = lane >> 4;
    int sw = (q ^ ((fr >> 1) & 3)) * 8;

    floatx4 acc[4][4] = {};

    for (int k0 = 0; k0 < K; k0 += 32) {
        stage128x32(A,  K, m0, k0, As, tid);
        stage128x32(Wt, K, n0, k0, Bs, tid);
        __syncthreads();
        short8 a[4], b[4];
        #pragma unroll
        for (int mi = 0; mi < 4; ++mi)
            a[mi] = *(const short8*)&As[(wm + mi * 16 + fr) * 32 + sw];
        #pragma unroll
        for (int ni = 0; ni < 4; ++ni)
            b[ni] = *(const short8*)&Bs[(wn + ni * 16 + fr) * 32 + sw];
        #pragma unroll
        for (int mi = 0; mi < 4; ++mi)
            #pragma unroll
            for (int ni = 0; ni < 4; ++ni)
                acc[mi][ni] = __builtin_amdgcn_mfma_f32_16x16x32_bf16(
                    a[mi], b[ni], acc[mi][ni], 0, 0, 0);
        __syncthreads();
    }

    #pragma unroll
    for (int ni = 0; ni < 4; ++ni) {
        int col = n0 + wn + ni * 16 + fr;
        float bsv = bias[col];
        #pragma unroll
        for (int mi = 0; mi < 4; ++mi)
            #pragma unroll
            for (int r = 0; r < 4; ++r) {
                int row = m0 + wm + mi * 16 + q * 4 + r;
                size_t idx = (size_t)row * ldC + col;
                C[idx] = acc[mi][ni][r] + bsv + C[idx];  // same-thread RMW
            }
    }
}

// ---------------------------------------------------------------------------
// Weight cast+transpose: W fp32 [K,N] -> Wt bf16 [N,K]
// ---------------------------------------------------------------------------
__global__ __launch_bounds__(256) void transpose_cast_kernel(
    const float* __restrict__ W, ushort* __restrict__ Wt, int K, int N)
{
    __shared__ float t[32][33];
    int lx = threadIdx.x & 31, ly = threadIdx.x >> 5;   // 32 x 8
    int n = blockIdx.x * 32 + lx;
    #pragma unroll
    for (int i = 0; i < 4; ++i) {
        int k = blockIdx.y * 32 + ly + i * 8;
        t[ly + i * 8][lx] = W[(size_t)k * N + n];
    }
    __syncthreads();
    int k2 = blockIdx.y * 32 + lx;
    #pragma unroll
    for (int i = 0; i < 4; ++i) {
        int n2 = blockIdx.x * 32 + ly + i * 8;
        Wt[(size_t)n2 * K + k2] = f2bf(t[lx][ly + i * 8]);
    }
}

// Batched version for the four 1024x1024 gate weights (grid.z picks source).
__global__ __launch_bounds__(256) void transpose_cast_gates(
    const float* __restrict__ w_i, const float* __restrict__ w_f,
    const float* __restrict__ w_g, const float* __restrict__ w_o,
    ushort* __restrict__ W1t, ushort* __restrict__ W2t)
{
    int z = blockIdx.z;
    const float* W = (z == 0) ? w_i : (z == 1) ? w_f : (z == 2) ? w_g : w_o;
    ushort* Wt = (z == 0) ? W1t : (z == 1) ? W1t + (size_t)1024 * Dd
               : (z == 2) ? W2t : W2t + (size_t)1024 * Dd;
    __shared__ float t[32][33];
    int lx = threadIdx.x & 31, ly = threadIdx.x >> 5;
    int n = blockIdx.x * 32 + lx;
    #pragma unroll
    for (int i = 0; i < 4; ++i) {
        int k = blockIdx.y * 32 + ly + i * 8;
        t[ly + i * 8][lx] = W[(size_t)k * Dd + n];
    }
    __syncthreads();
    int k2 = blockIdx.y * 32 + lx;
    #pragma unroll
    for (int i = 0; i < 4; ++i) {
        int n2 = blockIdx.x * 32 + ly + i * 8;
        Wt[(size_t)n2 * Dd + k2] = f2bf(t[lx][ly + i * 8]);
    }
}

// ---------------------------------------------------------------------------
// RMSNorm fp32 in -> bf16 out. One block per row.
// ---------------------------------------------------------------------------
__global__ __launch_bounds__(256) void rmsnorm_bf16_kernel(
    const float* __restrict__ x, const float* __restrict__ w,
    ushort* __restrict__ o)
{
    int row = blockIdx.x;
    int tid = threadIdx.x;
    float4 v = ((const float4*)(x + (size_t)row * Dd))[tid];
    float ss = v.x*v.x + v.y*v.y + v.z*v.z + v.w*v.w;
    #pragma unroll
    for (int off = 32; off > 0; off >>= 1) ss += __shfl_down(ss, off, 64);
    __shared__ float red[4];
    if ((tid & 63) == 0) red[tid >> 6] = ss;
    __syncthreads();
    float scale = rsqrtf((red[0] + red[1] + red[2] + red[3]) * (1.0f / Dd) + EPS);
    float4 wv = ((const float4*)w)[tid];
    us4 ov;
    ov.x = f2bf(v.x * scale * wv.x);
    ov.y = f2bf(v.y * scale * wv.y);
    ov.z = f2bf(v.z * scale * wv.z);
    ov.w = f2bf(v.w * scale * wv.w);
    *(us4*)&o[(size_t)row * Dd + tid * 4] = ov;
}

// ---------------------------------------------------------------------------
// Chunked linear recurrence, 4 channels/thread (ushort4 loads)
// ---------------------------------------------------------------------------
__global__ __launch_bounds__(256) void scan_pass1(
    const ushort* __restrict__ Ga, const ushort* __restrict__ Gb,
    float* __restrict__ P, float* __restrict__ Hend)
{
    int tid = threadIdx.x;
    int c = blockIdx.x, b = blockIdx.y;
    size_t base = ((size_t)b * Ll + (size_t)c * CS) * Dd + tid * 4;
    float p[4] = {1.f, 1.f, 1.f, 1.f};
    float h[4] = {};
    #pragma unroll 4
    for (int t = 0; t < CS; ++t) {
        us4 av = *(const us4*)&Ga[base + (size_t)t * Dd];
        us4 bv = *(const us4*)&Gb[base + (size_t)t * Dd];
        #pragma unroll
        for (int j = 0; j < 4; ++j) {
            float aa = bf2f(av[j]);
            float bb = bf2f(bv[j]);
            p[j] *= aa;
            h[j] = aa * h[j] + bb;
        }
    }
    size_t o = ((size_t)b * CH + c) * Dd + tid * 4;
    *(float4*)&P[o]    = make_float4(p[0], p[1], p[2], p[3]);
    *(float4*)&Hend[o] = make_float4(h[0], h[1], h[2], h[3]);
}

__global__ __launch_bounds__(256) void scan_pass2(
    const float* __restrict__ P, const float* __restrict__ Hend,
    const float* __restrict__ h0, float* __restrict__ Carry)
{
    int idx = blockIdx.x * 256 + threadIdx.x;  // B*D = 4096
    int b = idx / Dd, d = idx % Dd;
    float carry = h0[d];
    for (int c = 0; c < CH; ++c) {
        size_t o = ((size_t)b * CH + c) * Dd + d;
        Carry[o] = carry;
        carry = P[o] * carry + Hend[o];
    }
}

// Replay with carry + fused ogate/residual + fused RMSNorm2.
// Single barrier per t-step via parity double-buffered reduction slots:
// after barrier(t), every wave has finished reading slot (t&1) from t-1...
// writes at t+2 to the same slot are ordered behind barrier(t+1). Safe.
// ---------------------------------------------------------------------------
__global__ __launch_bounds__(256) void scan_pass3_norm(
    const ushort* __restrict__ Ga, const ushort* __restrict__ Gb,
    const ushort* __restrict__ Gog, const float* __restrict__ Carry,
    const float* __restrict__ x, const float* __restrict__ norm2w,
    float* __restrict__ x1, ushort* __restrict__ xnb)
{
    int tid = threadIdx.x;
    int c = blockIdx.x, b = blockIdx.y;
    size_t base = ((size_t)b * Ll + (size_t)c * CS) * Dd + tid * 4;
    float4 h4 = *(const float4*)&Carry[((size_t)b * CH + c) * Dd + tid * 4];
    float h[4] = {h4.x, h4.y, h4.z, h4.w};
    float4 w4 = ((const float4*)norm2w)[tid];
    float wv[4] = {w4.x, w4.y, w4.z, w4.w};
    __shared__ float red[2][4];

    for (int t = 0; t < CS; ++t) {
        size_t i = base + (size_t)t * Dd;
        us4 av = *(const us4*)&Ga[i];
        us4 bv = *(const us4*)&Gb[i];
        us4 gv = *(const us4*)&Gog[i];
        float4 xv = *(const float4*)&x[i];
        float xs[4] = {xv.x, xv.y, xv.z, xv.w};
        float v[4];
        #pragma unroll
        for (int j = 0; j < 4; ++j) {
            float aa = bf2f(av[j]);
            float bb = bf2f(bv[j]);
            h[j] = aa * h[j] + bb;
            v[j] = fast_tanh(h[j]) * bf2f(gv[j]) + xs[j];
        }
        *(float4*)&x1[i] = make_float4(v[0], v[1], v[2], v[3]);
        float ss = v[0]*v[0] + v[1]*v[1] + v[2]*v[2] + v[3]*v[3];
        #pragma unroll
        for (int off = 32; off > 0; off >>= 1) ss += __shfl_down(ss, off, 64);
        int slot = t & 1;
        if ((tid & 63) == 0) red[slot][tid >> 6] = ss;
        __syncthreads();
        float scale = rsqrtf((red[slot][0] + red[slot][1] + red[slot][2] +
                              red[slot][3]) * (1.0f / Dd) + EPS);
        us4 ov;
        #pragma unroll
        for (int j = 0; j < 4; ++j) ov[j] = f2bf(v[j] * scale * wv[j]);
        *(us4*)&xnb[i] = ov;
    }
}

// ---------------------------------------------------------------------------
// Launch. Workspace (195 MB):
//   [0,4)   MB: W1t gates bf16 [2048,1024]   (input | forget)
//   [4,8)   MB: W2t gates bf16 [2048,1024]   (igate | ogate)
//   [8,16)  MB: wtFC   [16,24) MB: wtFCA   [24,32) MB: wtOUT
//   [32,64) MB: xnb bf16 [M,1024]
//   [64,192)MB: Ga/Gb/Gog bf16 (32MB each) -> later hff bf16 [M,4096]
//   [192,195)MB: P, Hend, Carry fp32
// d_out doubles as x1 then final out.
// ---------------------------------------------------------------------------
extern "C" void kernel_launch(void* const* d_in, const int* in_sizes, int n_in,
                              void* d_out, int out_size, void* d_ws, size_t ws_size,
                              hipStream_t stream)
{
    const float* x        = (const float*)d_in[0];
    const float* w_forget = (const float*)d_in[1];
    const float* b_forget = (const float*)d_in[2];
    const float* w_input  = (const float*)d_in[3];
    const float* b_input  = (const float*)d_in[4];
    const float* w_igate  = (const float*)d_in[5];
    const float* b_igate  = (const float*)d_in[6];
    const float* w_ogate  = (const float*)d_in[7];
    const float* b_ogate  = (const float*)d_in[8];
    const float* h0       = (const float*)d_in[9];
    const float* norm1_w  = (const float*)d_in[10];
    const float* norm2_w  = (const float*)d_in[11];
    const float* w_fc     = (const float*)d_in[12];
    const float* b_fc     = (const float*)d_in[13];
    const float* w_fc_act = (const float*)d_in[14];
    const float* b_fc_act = (const float*)d_in[15];
    const float* w_out    = (const float*)d_in[16];
    const float* b_out    = (const float*)d_in[17];
    float* out = (float*)d_out;   // x1, then final out

    char* ws = (char*)d_ws;
    const size_t MB = 1ull << 20;
    ushort* wtG1  = (ushort*)(ws + 0 * MB);
    ushort* wtG2  = (ushort*)(ws + 4 * MB);
    ushort* wtFC  = (ushort*)(ws + 8 * MB);
    ushort* wtFCA = (ushort*)(ws + 16 * MB);
    ushort* wtOUT = (ushort*)(ws + 24 * MB);
    ushort* xnb   = (ushort*)(ws + 32 * MB);
    ushort* Ga    = (ushort*)(ws + 64 * MB);
    ushort* Gb    = (ushort*)(ws + 96 * MB);
    ushort* Gog   = (ushort*)(ws + 128 * MB);
    ushort* hff   = (ushort*)(ws + 64 * MB);   // [M,4096] bf16, reuses gate region
    float*  P     = (float*)(ws + 192 * MB);
    float*  Hend  = (float*)(ws + 193 * MB);
    float*  Carry = (float*)(ws + 194 * MB);

    // 0) weights -> bf16 [N,K]
    transpose_cast_gates<<<dim3(32, 32, 4), 256, 0, stream>>>(
        w_input, w_forget, w_igate, w_ogate, wtG1, wtG2);
    transpose_cast_kernel<<<dim3(DFF/32, Dd/32), 256, 0, stream>>>(w_fc,     wtFC,  Dd, DFF);
    transpose_cast_kernel<<<dim3(DFF/32, Dd/32), 256, 0, stream>>>(w_fc_act, wtFCA, Dd, DFF);
    transpose_cast_kernel<<<dim3(Dd/32, DFF/32), 256, 0, stream>>>(w_out,    wtOUT, DFF, Dd);

    // 1) xn = rmsnorm(x) -> bf16
    rmsnorm_bf16_kernel<<<Mm, 256, 0, stream>>>(x, norm1_w, xnb);

    // 2) all four gates in one dual-GEMM (N space = 2048, 64-wide tiles)
    dim3 gg(2048 / 64, Mm / 128);
    mfma_gemm_gates<<<gg, 256, 0, stream>>>(xnb, wtG1, wtG2,
                                            b_input, b_forget, b_igate, b_ogate,
                                            Ga, Gb, Gog, Dd);

    // 3) chunked scan + fused ogate/residual + fused rmsnorm2
    dim3 sg(CH, Bb);
    scan_pass1<<<sg, 256, 0, stream>>>(Ga, Gb, P, Hend);
    scan_pass2<<<(Bb * Dd) / 256, 256, 0, stream>>>(P, Hend, h0, Carry);
    scan_pass3_norm<<<sg, 256, 0, stream>>>(Ga, Gb, Gog, Carry, x, norm2_w,
                                            out, xnb);

    // 4) hff = (xn2@w_fc + b) * silu(xn2@w_fc_act + b)  -> bf16 [M,4096]
    dim3 gf(DFF / 64, Mm / 128);
    mfma_gemm_swiglu<<<gf, 256, 0, stream>>>(xnb, wtFC, b_fc, wtFCA, b_fc_act,
                                             hff, Dd, DFF);

    // 5) out = hff @ w_out + b_out + x1   (in-place on d_out)
    dim3 go(Dd / 128, Mm / 128);
    mfma_gemm_residual<<<go, 256, 0, stream>>>(hff, wtOUT, b_out, out, DFF, Dd);
}